// Round 12
// baseline (370.936 us; speedup 1.0000x reference)
//
#include <hip/hip_runtime.h>
#include <hip/hip_bf16.h>
#include <math.h>

#define NN 131072
#define HD 256

typedef __bf16 bf16;
typedef __attribute__((ext_vector_type(8))) __bf16 bf16x8;
typedef __attribute__((ext_vector_type(4))) __bf16 bf16x4;
typedef __attribute__((ext_vector_type(4))) float f32x4;

__device__ __forceinline__ float silu_f(float x) { return x / (1.f + __expf(-x)); }

__device__ __forceinline__ float bfu2f(unsigned int lo16) {
    unsigned int u = lo16 << 16;
    return __builtin_bit_cast(float, u);
}
__device__ __forceinline__ unsigned short f2bfu(float f) {
    bf16 b = (bf16)f;
    return __builtin_bit_cast(unsigned short, b);
}
__device__ __forceinline__ uint2 pack4(float a, float b, float c, float d) {
    uint2 v;
    v.x = (unsigned int)f2bfu(a) | ((unsigned int)f2bfu(b) << 16);
    v.y = (unsigned int)f2bfu(c) | ((unsigned int)f2bfu(d) << 16);
    return v;
}

// A-tile (LDS bf16, stride 264) x packed-B -> acc[RN][4]; wave covers RN*16 rows x 64
// cols (col-blocks wave*4+c). 2-deep B prefetch. Unswapped layout:
// lane holds (m = 16r+4lkhi+q, n = 16(4w+c)+lrow).
template<int KS, int RN>
__device__ __forceinline__ void mmR(const bf16* Xl, int bk0, const bf16x8* __restrict__ Bp,
                                    int wave, int lane, f32x4 acc[RN][4]) {
    const int lrow = lane & 15, lkhi = lane >> 4;
    bf16x8 bcur[4], bnxt[4];
    #pragma unroll
    for (int c = 0; c < 4; ++c)
        bcur[c] = Bp[(bk0 * 16 + wave * 4 + c) * 64 + lane];
    #pragma unroll
    for (int ks = 0; ks < KS; ++ks) {
        if (ks + 1 < KS) {
            #pragma unroll
            for (int c = 0; c < 4; ++c)
                bnxt[c] = Bp[((bk0 + ks + 1) * 16 + wave * 4 + c) * 64 + lane];
        }
        bf16x8 a[RN];
        #pragma unroll
        for (int r = 0; r < RN; ++r)
            a[r] = *(const bf16x8*)&Xl[(r * 16 + lrow) * 264 + ks * 32 + lkhi * 8];
        #pragma unroll
        for (int c = 0; c < 4; ++c)
            #pragma unroll
            for (int r = 0; r < RN; ++r)
                acc[r][c] = __builtin_amdgcn_mfma_f32_16x16x32_bf16(a[r], bcur[c], acc[r][c], 0, 0, 0);
        #pragma unroll
        for (int c = 0; c < 4; ++c) bcur[c] = bnxt[c];
    }
}

// ---------------- weight packing ----------------
__device__ __forceinline__ void packW(const float* __restrict__ W, bf16* __restrict__ P, int idx) {
    int j  = idx & 7;
    int ln = (idx >> 3) & 63;
    int cb = (idx >> 9) & 15;
    int ks = idx >> 13;
    int k = ks * 32 + ((ln >> 4) << 3) + j;
    int n = (cb << 4) + (ln & 15);
    P[idx] = (bf16)W[k * HD + n];
}

__global__ void pack_kernel(const float* __restrict__ ew1, const float* __restrict__ ew2,
                            const float* __restrict__ pw1, const float* __restrict__ nw1,
                            const float* __restrict__ nw2,
                            bf16* __restrict__ ew1p, bf16* __restrict__ ew2p,
                            bf16* __restrict__ pw1p, bf16* __restrict__ nw1p,
                            bf16* __restrict__ nw2p) {
    int t = blockIdx.x * 256 + threadIdx.x;
    if (t < 131072) { packW(ew1, ew1p, t); return; }
    t -= 131072;
    if (t < 65536)  { packW(ew2, ew2p, t); return; }
    t -= 65536;
    if (t < 65536)  { packW(pw1, pw1p, t); return; }
    t -= 65536;
    if (t < 131072) { packW(nw1, nw1p, t); return; }
    t -= 131072;
    if (t < 65536)  { packW(nw2, nw2p, t); return; }
}

// ---------------- edge kernel ----------------
// 32 edges/block, 256 threads, (256,4): ~90 live regs under the 128 cap ->
// 4 blocks/CU = 16 waves/CU. Phase chain / layouts identical to R7.
__global__ __launch_bounds__(256, 4) void edge_kernel(
    const float* __restrict__ h, const float* __restrict__ pos,
    const float* __restrict__ ew1, const float* __restrict__ eb1,
    const float* __restrict__ eb2, const float* __restrict__ pb1,
    const float* __restrict__ pw2,
    const bf16x8* __restrict__ ew1p, const bf16x8* __restrict__ ew2p,
    const bf16x8* __restrict__ pw1p, const bf16x8* __restrict__ nw1p,
    bf16* __restrict__ q1_g, uint2* __restrict__ p1_g,
    float* __restrict__ dp_g) {
    __shared__ bf16 X[33 * 264];          // h rows -> t1 -> ea -> q1 (in place)
    __shared__ float dist_s[32];
    __shared__ float dp_s[4][32][3];

    const int tid = threadIdx.x;
    const int lane = tid & 63, wave = tid >> 6;
    const int lrow = lane & 15, lkhi = lane >> 4;
    const int e0 = blockIdx.x * 32;

    // stage h rows e0..e0+32 (bf16)
    for (int idx = tid; idx < 33 * 64; idx += 256) {
        int r = idx >> 6, c4 = (idx & 63) << 2;
        int gr = e0 + r;
        float4 v = make_float4(0.f, 0.f, 0.f, 0.f);
        if (gr < NN) v = *(const float4*)&h[(size_t)gr * HD + c4];
        bf16x4 b;
        b[0] = (bf16)v.x; b[1] = (bf16)v.y; b[2] = (bf16)v.z; b[3] = (bf16)v.w;
        *(bf16x4*)&X[r * 264 + c4] = b;
    }
    if (tid < 32) {
        int e = e0 + tid;
        float d = 0.f;
        if (e < NN - 1) {
            float dx = pos[3 * e + 3] - pos[3 * e];
            float dy = pos[3 * e + 4] - pos[3 * e + 1];
            float dz = pos[3 * e + 5] - pos[3 * e + 2];
            d = sqrtf(dx * dx + dy * dy + dz * dz);
        }
        dist_s[tid] = d;
    }
    // hoisted per-lane params (unswapped layout: n = 16(4w+c)+lrow)
    float bias1[4], bias2[4], bias3[4], wlast[4], w2l[4][3];
    #pragma unroll
    for (int c = 0; c < 4; ++c) {
        int n = (wave * 4 + c) * 16 + lrow;
        bias1[c] = eb1[n];
        bias2[c] = eb2[n];
        bias3[c] = pb1[n];
        wlast[c] = ew1[512 * HD + n];
        #pragma unroll
        for (int x = 0; x < 3; ++x) w2l[c][x] = pw2[n * 3 + x];
    }
    __syncthreads();

    f32x4 acc[2][4];

    // P0: p1 = h @ nw1[:256] -> uint2 fragment chunks (no barrier needed after)
    #pragma unroll
    for (int r = 0; r < 2; ++r)
        #pragma unroll
        for (int c = 0; c < 4; ++c) acc[r][c] = (f32x4)0.f;
    mmR<8, 2>(X, 0, nw1p, wave, lane, acc);
    {
        uint2* w = p1_g + ((size_t)blockIdx.x * 4 + wave) * 512;
        #pragma unroll
        for (int r = 0; r < 2; ++r)
            #pragma unroll
            for (int c = 0; c < 4; ++c)
                w[(r * 4 + c) * 64 + lane] =
                    pack4(acc[r][c][0], acc[r][c][1], acc[r][c][2], acc[r][c][3]);
    }

    // P1: t1 = silu(edge_feat @ ew1 + eb1 + dist*ew1[512]); 16 ks (rb trick), prefetch
    #pragma unroll
    for (int r = 0; r < 2; ++r)
        #pragma unroll
        for (int c = 0; c < 4; ++c) acc[r][c] = (f32x4)0.f;
    {
        bf16x8 bcur[4], bnxt[4];
        #pragma unroll
        for (int c = 0; c < 4; ++c)
            bcur[c] = ew1p[(wave * 4 + c) * 64 + lane];
        #pragma unroll
        for (int ks = 0; ks < 16; ++ks) {
            if (ks < 15) {
                #pragma unroll
                for (int c = 0; c < 4; ++c)
                    bnxt[c] = ew1p[((ks + 1) * 16 + wave * 4 + c) * 64 + lane];
            }
            const int rb = (ks >= 8) ? 1 : 0;
            const int kk = ks * 32 + lkhi * 8 - rb * 256;
            bf16x8 a[2];
            #pragma unroll
            for (int r = 0; r < 2; ++r)
                a[r] = *(const bf16x8*)&X[(r * 16 + lrow + rb) * 264 + kk];
            #pragma unroll
            for (int c = 0; c < 4; ++c)
                #pragma unroll
                for (int r = 0; r < 2; ++r)
                    acc[r][c] = __builtin_amdgcn_mfma_f32_16x16x32_bf16(a[r], bcur[c], acc[r][c], 0, 0, 0);
            #pragma unroll
            for (int c = 0; c < 4; ++c) bcur[c] = bnxt[c];
        }
    }
    __syncthreads();  // all P0/P1 reads of X done
    #pragma unroll
    for (int r = 0; r < 2; ++r)
        #pragma unroll
        for (int c = 0; c < 4; ++c)
            #pragma unroll
            for (int q = 0; q < 4; ++q) {
                int row = r * 16 + lkhi * 4 + q;
                int col = (wave * 4 + c) * 16 + lrow;
                float v = acc[r][c][q] + dist_s[row] * wlast[c] + bias1[c];
                X[row * 264 + col] = (bf16)silu_f(v);  // t1 in place
            }
    __syncthreads();

    // P2: ea = t1 @ ew2 + eb2 (in place)
    #pragma unroll
    for (int r = 0; r < 2; ++r)
        #pragma unroll
        for (int c = 0; c < 4; ++c) acc[r][c] = (f32x4)0.f;
    mmR<8, 2>(X, 0, ew2p, wave, lane, acc);
    __syncthreads();
    #pragma unroll
    for (int r = 0; r < 2; ++r)
        #pragma unroll
        for (int c = 0; c < 4; ++c)
            #pragma unroll
            for (int q = 0; q < 4; ++q) {
                int row = r * 16 + lkhi * 4 + q;
                int col = (wave * 4 + c) * 16 + lrow;
                X[row * 264 + col] = (bf16)(acc[r][c][q] + bias2[c]);  // ea in place
            }
    __syncthreads();

    // P3a: t3 = silu(ea @ pw1 + pb1) in regs; dp = t3 @ pw2 reg-reduced
    #pragma unroll
    for (int r = 0; r < 2; ++r)
        #pragma unroll
        for (int c = 0; c < 4; ++c) acc[r][c] = (f32x4)0.f;
    mmR<8, 2>(X, 0, pw1p, wave, lane, acc);
    #pragma unroll
    for (int r = 0; r < 2; ++r) {
        float red[12];
        #pragma unroll
        for (int q = 0; q < 4; ++q) {
            float t3v[4];
            #pragma unroll
            for (int c = 0; c < 4; ++c) t3v[c] = silu_f(acc[r][c][q] + bias3[c]);
            #pragma unroll
            for (int x = 0; x < 3; ++x) {
                float s = 0.f;
                #pragma unroll
                for (int c = 0; c < 4; ++c) s += t3v[c] * w2l[c][x];
                red[q * 3 + x] = s;
            }
        }
        #pragma unroll
        for (int i = 0; i < 12; ++i) {
            float v = red[i];
            v += __shfl_xor(v, 1);
            v += __shfl_xor(v, 2);
            v += __shfl_xor(v, 4);
            v += __shfl_xor(v, 8);
            red[i] = v;
        }
        if (lrow == 0) {
            #pragma unroll
            for (int q = 0; q < 4; ++q)
                #pragma unroll
                for (int x = 0; x < 3; ++x)
                    dp_s[wave][16 * r + 4 * lkhi + q][x] = red[q * 3 + x];
        }
    }

    // P3b: q1 = ea @ nw1[256:512] (same X state — no barrier needed)
    #pragma unroll
    for (int r = 0; r < 2; ++r)
        #pragma unroll
        for (int c = 0; c < 4; ++c) acc[r][c] = (f32x4)0.f;
    mmR<8, 2>(X, 8, nw1p, wave, lane, acc);

    __syncthreads();  // all X reads done + dp_s visible
    // overlay X = q1
    #pragma unroll
    for (int r = 0; r < 2; ++r)
        #pragma unroll
        for (int c = 0; c < 4; ++c)
            #pragma unroll
            for (int q = 0; q < 4; ++q) {
                int row = r * 16 + lkhi * 4 + q;
                int col = (wave * 4 + c) * 16 + lrow;
                X[row * 264 + col] = (bf16)acc[r][c][q];
            }
    if (tid < 96) {
        int row = tid / 3, x = tid - row * 3;
        float s = dp_s[0][row][x] + dp_s[1][row][x] + dp_s[2][row][x] + dp_s[3][row][x];
        dp_g[(size_t)(e0 + row) * 3 + x] = s;
    }
    __syncthreads();
    // q1 -> global (row layout, coalesced)
    for (int idx = tid; idx < 32 * 128; idx += 256) {
        int r = idx >> 7, cu = idx & 127;
        ((unsigned int*)&q1_g[(size_t)(e0 + r) * HD])[cu] = ((const unsigned int*)&X[r * 264])[cu];
    }
}

// ---------------- node kernel ----------------
// 64 nodes/block; p1 chunks come from TWO 32-edge blocks (2n, 2n+1).
// t4 = silu(p1[i] + q1[i] + q1[i-1] + nb1); h_out = t4 @ nw2 + nb2.
__global__ __launch_bounds__(256, 4) void node_kernel(
    const float* __restrict__ pos,
    const float* __restrict__ nb1, const float* __restrict__ nb2,
    const bf16x8* __restrict__ nw2p,
    const bf16* __restrict__ q1_g, const uint2* __restrict__ p1_g,
    const float* __restrict__ dp_g,
    float* __restrict__ h_out, float* __restrict__ pos_out) {
    __shared__ bf16 X[65 * 264];   // q1 halo (slot t = q1[n0-1+t]) -> t4 rows 0..63

    const int tid = threadIdx.x;
    const int lane = tid & 63, wave = tid >> 6;
    const int lrow = lane & 15, lkhi = lane >> 4;
    const int n0 = blockIdx.x * 64;

    // pos head
    if (tid < 192) {
        int row = tid & 63, col = tid >> 6;
        int i = n0 + row;
        float dpi = (i < NN - 1) ? dp_g[(size_t)i * 3 + col] : 0.f;
        float dpm = (i > 0) ? dp_g[(size_t)(i - 1) * 3 + col] : 0.f;
        pos_out[(size_t)i * 3 + col] = pos[(size_t)i * 3 + col] + 0.1f * (dpi - dpm);
    }

    // stage q1 halo, uint4-vectorized
    for (int idx = tid; idx < 65 * 32; idx += 256) {
        int t = idx >> 5, cu = idx & 31;
        int er = n0 - 1 + t;
        uint4 v = make_uint4(0u, 0u, 0u, 0u);
        if (er >= 0 && er <= NN - 2) v = ((const uint4*)&q1_g[(size_t)er * HD])[cu];
        ((uint4*)&X[t * 264])[cu] = v;
    }
    // early p1 fragment loads (coalesced uint2); rows 16r come from edge block
    // 2*blockIdx.x + (r>>1), local row-block r&1.
    uint2 p1r[16];
    #pragma unroll
    for (int r = 0; r < 4; ++r) {
        const uint2* pp = p1_g + (((size_t)blockIdx.x * 2 + (r >> 1)) * 4 + wave) * 512;
        #pragma unroll
        for (int c = 0; c < 4; ++c)
            p1r[r * 4 + c] = pp[((r & 1) * 4 + c) * 64 + lane];
    }
    float b1[4];
    #pragma unroll
    for (int c = 0; c < 4; ++c) b1[c] = nb1[(wave * 4 + c) * 16 + lrow];
    __syncthreads();

    // elementwise t4 = silu(p1 + q1[i] + q1[i-1] + b1), held in regs
    unsigned int t4p[32];
    #pragma unroll
    for (int r = 0; r < 4; ++r)
        #pragma unroll
        for (int c = 0; c < 4; ++c) {
            int i = r * 4 + c;
            int col = (wave * 4 + c) * 16 + lrow;
            #pragma unroll
            for (int qh = 0; qh < 2; ++qh) {
                unsigned int pk = qh == 0 ? p1r[i].x : p1r[i].y;
                unsigned int outp = 0;
                #pragma unroll
                for (int j = 0; j < 2; ++j) {
                    int q = 2 * qh + j;
                    int row = r * 16 + lkhi * 4 + q;
                    float p1v = bfu2f(j == 0 ? (pk & 0xffffu) : (pk >> 16));
                    float z = p1v + (float)X[(row + 1) * 264 + col] + (float)X[row * 264 + col] + b1[c];
                    unsigned short tb = f2bfu(silu_f(z));
                    outp |= (unsigned int)tb << (16 * j);
                }
                t4p[i * 2 + qh] = outp;
            }
        }
    __syncthreads();  // all q1 reads done
    // write t4 tile (rows 0..63)
    #pragma unroll
    for (int r = 0; r < 4; ++r)
        #pragma unroll
        for (int c = 0; c < 4; ++c) {
            int i = r * 4 + c;
            int col = (wave * 4 + c) * 16 + lrow;
            #pragma unroll
            for (int q = 0; q < 4; ++q) {
                int row = r * 16 + lkhi * 4 + q;
                unsigned int pk = t4p[i * 2 + (q >> 1)];
                unsigned short tb = (unsigned short)((q & 1) ? (pk >> 16) : (pk & 0xffffu));
                X[row * 264 + col] = __builtin_bit_cast(bf16, tb);
            }
        }
    __syncthreads();

    // P2: h_out = t4 @ nw2 + nb2
    f32x4 acc[4][4];
    #pragma unroll
    for (int r = 0; r < 4; ++r)
        #pragma unroll
        for (int c = 0; c < 4; ++c) acc[r][c] = (f32x4)0.f;
    mmR<8, 4>(X, 0, nw2p, wave, lane, acc);
    float b2[4];
    #pragma unroll
    for (int c = 0; c < 4; ++c) b2[c] = nb2[(wave * 4 + c) * 16 + lrow];
    #pragma unroll
    for (int r = 0; r < 4; ++r)
        #pragma unroll
        for (int c = 0; c < 4; ++c)
            #pragma unroll
            for (int q = 0; q < 4; ++q) {
                int row = r * 16 + lkhi * 4 + q;
                int col = (wave * 4 + c) * 16 + lrow;
                h_out[(size_t)(n0 + row) * HD + col] = acc[r][c][q] + b2[c];
            }
}

// ---------------- launch ----------------
extern "C" void kernel_launch(void* const* d_in, const int* in_sizes, int n_in,
                              void* d_out, int out_size, void* d_ws, size_t ws_size,
                              hipStream_t stream) {
    const float* h   = (const float*)d_in[0];
    const float* pos = (const float*)d_in[1];
    const float* ew1 = (const float*)d_in[2];
    const float* eb1 = (const float*)d_in[3];
    const float* ew2 = (const float*)d_in[4];
    const float* eb2 = (const float*)d_in[5];
    const float* pw1 = (const float*)d_in[6];
    const float* pb1 = (const float*)d_in[7];
    const float* pw2 = (const float*)d_in[8];
    const float* nw1 = (const float*)d_in[9];
    const float* nb1 = (const float*)d_in[10];
    const float* nw2 = (const float*)d_in[11];
    const float* nb2 = (const float*)d_in[12];

    char* ws = (char*)d_ws;
    bf16*  q1   = (bf16*)ws;                      // 67108864 B
    float* dp   = (float*)(ws + 67108864);        // 1572864 B
    uint2* p1   = (uint2*)(ws + 68681728);        // 67108864 B
    char*  wsw = ws + 135790592;
    bf16*  ew1p = (bf16*)(wsw);                   // 262144 B
    bf16*  ew2p = (bf16*)(wsw + 262144);          // 131072 B
    bf16*  pw1p = (bf16*)(wsw + 393216);          // 131072 B
    bf16*  nw1p = (bf16*)(wsw + 524288);          // 262144 B
    bf16*  nw2p = (bf16*)(wsw + 786432);          // 131072 B

    float* out = (float*)d_out;
    float* h_out = out;
    float* pos_out = out + (size_t)NN * HD;

    pack_kernel<<<1792, 256, 0, stream>>>(ew1, ew2, pw1, nw1, nw2,
                                          ew1p, ew2p, pw1p, nw1p, nw2p);
    edge_kernel<<<4096, 256, 0, stream>>>(h, pos, ew1, eb1, eb2, pb1, pw2,
                                          (const bf16x8*)ew1p, (const bf16x8*)ew2p,
                                          (const bf16x8*)pw1p, (const bf16x8*)nw1p,
                                          q1, p1, dp);
    node_kernel<<<2048, 256, 0, stream>>>(pos, nb1, nb2,
                                          (const bf16x8*)nw2p,
                                          q1, (const uint2*)p1, dp, h_out, pos_out);
}

// Round 13
// 259.590 us; speedup vs baseline: 1.4289x; 1.4289x over previous
//
#include <hip/hip_runtime.h>
#include <hip/hip_bf16.h>
#include <math.h>

#define NN 131072
#define HD 256

typedef __bf16 bf16;
typedef __attribute__((ext_vector_type(8))) __bf16 bf16x8;
typedef __attribute__((ext_vector_type(4))) __bf16 bf16x4;
typedef __attribute__((ext_vector_type(4))) float f32x4;

__device__ __forceinline__ float silu_f(float x) { return x / (1.f + __expf(-x)); }

__device__ __forceinline__ float bfu2f(unsigned int lo16) {
    unsigned int u = lo16 << 16;
    return __builtin_bit_cast(float, u);
}
__device__ __forceinline__ unsigned short f2bfu(float f) {
    bf16 b = (bf16)f;
    return __builtin_bit_cast(unsigned short, b);
}
__device__ __forceinline__ uint2 pack4(float a, float b, float c, float d) {
    uint2 v;
    v.x = (unsigned int)f2bfu(a) | ((unsigned int)f2bfu(b) << 16);
    v.y = (unsigned int)f2bfu(c) | ((unsigned int)f2bfu(d) << 16);
    return v;
}

// Depth-2 B prefetch (node kernel: (256,4) cap leaves no headroom for more).
template<int KSTEPS, int RN>
__device__ __forceinline__ void mm_tileR(const bf16* Xl, int bk0, const bf16x8* __restrict__ Bp,
                                         int wave, int lane, f32x4 acc[RN][4]) {
    const int lrow = lane & 15, lkhi = lane >> 4;
    bf16x8 bcur[4], bnxt[4];
    #pragma unroll
    for (int c = 0; c < 4; ++c)
        bcur[c] = Bp[(bk0 * 16 + wave * 4 + c) * 64 + lane];
    #pragma unroll
    for (int ks = 0; ks < KSTEPS; ++ks) {
        if (ks + 1 < KSTEPS) {
            #pragma unroll
            for (int c = 0; c < 4; ++c)
                bnxt[c] = Bp[((bk0 + ks + 1) * 16 + wave * 4 + c) * 64 + lane];
        }
        bf16x8 a[RN];
        #pragma unroll
        for (int r = 0; r < RN; ++r)
            a[r] = *(const bf16x8*)&Xl[(r * 16 + lrow) * 264 + ks * 32 + lkhi * 8];
        #pragma unroll
        for (int c = 0; c < 4; ++c)
            #pragma unroll
            for (int r = 0; r < RN; ++r)
                acc[r][c] = __builtin_amdgcn_mfma_f32_16x16x32_bf16(a[r], bcur[c], acc[r][c], 0, 0, 0);
        #pragma unroll
        for (int c = 0; c < 4; ++c) bcur[c] = bnxt[c];
    }
}

// Depth-3 B prefetch (edge kernel: (256,3) cap ~170, 100 VGPR + 64 AGPR fits).
template<int KSTEPS, int RN>
__device__ __forceinline__ void mm_tileR3(const bf16* Xl, int bk0, const bf16x8* __restrict__ Bp,
                                          int wave, int lane, f32x4 acc[RN][4]) {
    const int lrow = lane & 15, lkhi = lane >> 4;
    bf16x8 b0[4], b1[4], b2[4];
    #pragma unroll
    for (int c = 0; c < 4; ++c) {
        b0[c] = Bp[(bk0 * 16 + wave * 4 + c) * 64 + lane];
        b1[c] = Bp[((bk0 + 1) * 16 + wave * 4 + c) * 64 + lane];
    }
    #pragma unroll
    for (int ks = 0; ks < KSTEPS; ++ks) {
        if (ks + 2 < KSTEPS) {
            #pragma unroll
            for (int c = 0; c < 4; ++c)
                b2[c] = Bp[((bk0 + ks + 2) * 16 + wave * 4 + c) * 64 + lane];
        }
        bf16x8 a[RN];
        #pragma unroll
        for (int r = 0; r < RN; ++r)
            a[r] = *(const bf16x8*)&Xl[(r * 16 + lrow) * 264 + ks * 32 + lkhi * 8];
        #pragma unroll
        for (int c = 0; c < 4; ++c)
            #pragma unroll
            for (int r = 0; r < RN; ++r)
                acc[r][c] = __builtin_amdgcn_mfma_f32_16x16x32_bf16(a[r], b0[c], acc[r][c], 0, 0, 0);
        #pragma unroll
        for (int c = 0; c < 4; ++c) { b0[c] = b1[c]; b1[c] = b2[c]; }
    }
}

// ---------------- weight packing ----------------
__device__ __forceinline__ void packW(const float* __restrict__ W, bf16* __restrict__ P, int idx) {
    int j  = idx & 7;
    int ln = (idx >> 3) & 63;
    int cb = (idx >> 9) & 15;
    int ks = idx >> 13;
    int k = ks * 32 + ((ln >> 4) << 3) + j;
    int n = (cb << 4) + (ln & 15);
    P[idx] = (bf16)W[k * HD + n];
}

__global__ void pack_kernel(const float* __restrict__ ew1, const float* __restrict__ ew2,
                            const float* __restrict__ pw1, const float* __restrict__ nw1,
                            const float* __restrict__ nw2,
                            bf16* __restrict__ ew1p, bf16* __restrict__ ew2p,
                            bf16* __restrict__ pw1p, bf16* __restrict__ nw1p,
                            bf16* __restrict__ nw2p) {
    int t = blockIdx.x * 256 + threadIdx.x;
    if (t < 131072) { packW(ew1, ew1p, t); return; }
    t -= 131072;
    if (t < 65536)  { packW(ew2, ew2p, t); return; }
    t -= 65536;
    if (t < 65536)  { packW(pw1, pw1p, t); return; }
    t -= 65536;
    if (t < 131072) { packW(nw1, nw1p, t); return; }
    t -= 131072;
    if (t < 65536)  { packW(nw2, nw2p, t); return; }
}

// ---------------- edge kernel ----------------
// 64 edges/block, single LDS buffer, (256,3): reg headroom for depth-3 B-prefetch.
__global__ __launch_bounds__(256, 3) void edge_kernel(
    const float* __restrict__ h, const float* __restrict__ pos,
    const float* __restrict__ ew1, const float* __restrict__ eb1,
    const float* __restrict__ eb2, const float* __restrict__ pb1,
    const float* __restrict__ pw2,
    const bf16x8* __restrict__ ew1p, const bf16x8* __restrict__ ew2p,
    const bf16x8* __restrict__ pw1p, const bf16x8* __restrict__ nw1p,
    bf16* __restrict__ q1_g, uint2* __restrict__ p1_g,
    float* __restrict__ dp_g) {
    __shared__ bf16 X[65 * 264];          // h rows -> t1 -> ea -> q1 (in place)
    __shared__ float dist_s[64];
    __shared__ float dp_s[4][64][3];

    const int tid = threadIdx.x;
    const int lane = tid & 63, wave = tid >> 6;
    const int lrow = lane & 15, lkhi = lane >> 4;
    const int e0 = blockIdx.x * 64;

    // stage h rows e0..e0+64 (bf16)
    for (int idx = tid; idx < 65 * 64; idx += 256) {
        int r = idx >> 6, c4 = (idx & 63) << 2;
        int gr = e0 + r;
        float4 v = make_float4(0.f, 0.f, 0.f, 0.f);
        if (gr < NN) v = *(const float4*)&h[(size_t)gr * HD + c4];
        bf16x4 b;
        b[0] = (bf16)v.x; b[1] = (bf16)v.y; b[2] = (bf16)v.z; b[3] = (bf16)v.w;
        *(bf16x4*)&X[r * 264 + c4] = b;
    }
    if (tid < 64) {
        int e = e0 + tid;
        float d = 0.f;
        if (e < NN - 1) {
            float dx = pos[3 * e + 3] - pos[3 * e];
            float dy = pos[3 * e + 4] - pos[3 * e + 1];
            float dz = pos[3 * e + 5] - pos[3 * e + 2];
            d = sqrtf(dx * dx + dy * dy + dz * dz);
        }
        dist_s[tid] = d;
    }
    // per-lane uniform params (unswapped layout: n = 16(4w+c)+lrow)
    float bias1[4], bias2[4], bias3[4], wlast[4], w2l[4][3];
    #pragma unroll
    for (int c = 0; c < 4; ++c) {
        int col = (wave * 4 + c) * 16 + lrow;
        bias1[c] = eb1[col];
        bias2[c] = eb2[col];
        bias3[c] = pb1[col];
        wlast[c] = ew1[512 * HD + col];
        #pragma unroll
        for (int x = 0; x < 3; ++x) w2l[c][x] = pw2[col * 3 + x];
    }
    __syncthreads();

    f32x4 acc[4][4];

    // P0: p1 = h @ nw1[:256] -> uint2 fragment chunks
    #pragma unroll
    for (int r = 0; r < 4; ++r)
        #pragma unroll
        for (int c = 0; c < 4; ++c) acc[r][c] = (f32x4)0.f;
    mm_tileR3<8, 4>(X, 0, nw1p, wave, lane, acc);
    {
        uint2* w = p1_g + ((size_t)blockIdx.x * 4 + wave) * 1024;
        #pragma unroll
        for (int r = 0; r < 4; ++r)
            #pragma unroll
            for (int c = 0; c < 4; ++c)
                w[(r * 4 + c) * 64 + lane] =
                    pack4(acc[r][c][0], acc[r][c][1], acc[r][c][2], acc[r][c][3]);
    }

    // P1: t1 = silu(edge_feat @ ew1 + eb1 + dist*ew1[512]); 16 ks (rb trick), depth-3
    #pragma unroll
    for (int r = 0; r < 4; ++r)
        #pragma unroll
        for (int c = 0; c < 4; ++c) acc[r][c] = (f32x4)0.f;
    {
        bf16x8 b0[4], b1[4], b2[4];
        #pragma unroll
        for (int c = 0; c < 4; ++c) {
            b0[c] = ew1p[(wave * 4 + c) * 64 + lane];
            b1[c] = ew1p[(16 + wave * 4 + c) * 64 + lane];
        }
        #pragma unroll
        for (int ks = 0; ks < 16; ++ks) {
            if (ks < 14) {
                #pragma unroll
                for (int c = 0; c < 4; ++c)
                    b2[c] = ew1p[((ks + 2) * 16 + wave * 4 + c) * 64 + lane];
            }
            const int rb = (ks >= 8) ? 1 : 0;
            const int kk = ks * 32 + lkhi * 8 - rb * 256;
            bf16x8 a[4];
            #pragma unroll
            for (int r = 0; r < 4; ++r)
                a[r] = *(const bf16x8*)&X[(r * 16 + lrow + rb) * 264 + kk];
            #pragma unroll
            for (int c = 0; c < 4; ++c)
                #pragma unroll
                for (int r = 0; r < 4; ++r)
                    acc[r][c] = __builtin_amdgcn_mfma_f32_16x16x32_bf16(a[r], b0[c], acc[r][c], 0, 0, 0);
            #pragma unroll
            for (int c = 0; c < 4; ++c) { b0[c] = b1[c]; b1[c] = b2[c]; }
        }
    }
    __syncthreads();  // all P0/P1 reads of X done
    #pragma unroll
    for (int r = 0; r < 4; ++r)
        #pragma unroll
        for (int c = 0; c < 4; ++c)
            #pragma unroll
            for (int q = 0; q < 4; ++q) {
                int row = r * 16 + lkhi * 4 + q;
                int col = (wave * 4 + c) * 16 + lrow;
                float v = acc[r][c][q] + dist_s[row] * wlast[c] + bias1[c];
                X[row * 264 + col] = (bf16)silu_f(v);  // t1 in place
            }
    __syncthreads();

    // P2: ea = t1 @ ew2 + eb2 (in place)
    #pragma unroll
    for (int r = 0; r < 4; ++r)
        #pragma unroll
        for (int c = 0; c < 4; ++c) acc[r][c] = (f32x4)0.f;
    mm_tileR3<8, 4>(X, 0, ew2p, wave, lane, acc);
    __syncthreads();
    #pragma unroll
    for (int r = 0; r < 4; ++r)
        #pragma unroll
        for (int c = 0; c < 4; ++c)
            #pragma unroll
            for (int q = 0; q < 4; ++q) {
                int row = r * 16 + lkhi * 4 + q;
                int col = (wave * 4 + c) * 16 + lrow;
                X[row * 264 + col] = (bf16)(acc[r][c][q] + bias2[c]);  // ea in place
            }
    __syncthreads();

    // P3a: t3 = silu(ea @ pw1 + pb1) in regs; dp = t3 @ pw2 reg-reduced
    #pragma unroll
    for (int r = 0; r < 4; ++r)
        #pragma unroll
        for (int c = 0; c < 4; ++c) acc[r][c] = (f32x4)0.f;
    mm_tileR3<8, 4>(X, 0, pw1p, wave, lane, acc);
    #pragma unroll
    for (int r = 0; r < 4; ++r) {
        float red[12];
        #pragma unroll
        for (int q = 0; q < 4; ++q) {
            float t3v[4];
            #pragma unroll
            for (int c = 0; c < 4; ++c) t3v[c] = silu_f(acc[r][c][q] + bias3[c]);
            #pragma unroll
            for (int x = 0; x < 3; ++x) {
                float s = 0.f;
                #pragma unroll
                for (int c = 0; c < 4; ++c) s += t3v[c] * w2l[c][x];
                red[q * 3 + x] = s;
            }
        }
        #pragma unroll
        for (int i = 0; i < 12; ++i) {
            float v = red[i];
            v += __shfl_xor(v, 1);
            v += __shfl_xor(v, 2);
            v += __shfl_xor(v, 4);
            v += __shfl_xor(v, 8);
            red[i] = v;
        }
        if (lrow == 0) {
            #pragma unroll
            for (int q = 0; q < 4; ++q)
                #pragma unroll
                for (int x = 0; x < 3; ++x)
                    dp_s[wave][16 * r + 4 * lkhi + q][x] = red[q * 3 + x];
        }
    }

    // P3b: q1 = ea @ nw1[256:512] (same X state — no barrier needed)
    #pragma unroll
    for (int r = 0; r < 4; ++r)
        #pragma unroll
        for (int c = 0; c < 4; ++c) acc[r][c] = (f32x4)0.f;
    mm_tileR3<8, 4>(X, 8, nw1p, wave, lane, acc);

    __syncthreads();  // all X reads done + dp_s visible
    // overlay X = q1
    #pragma unroll
    for (int r = 0; r < 4; ++r)
        #pragma unroll
        for (int c = 0; c < 4; ++c)
            #pragma unroll
            for (int q = 0; q < 4; ++q) {
                int row = r * 16 + lkhi * 4 + q;
                int col = (wave * 4 + c) * 16 + lrow;
                X[row * 264 + col] = (bf16)acc[r][c][q];
            }
    if (tid < 192) {
        int row = tid / 3, x = tid - row * 3;
        float s = dp_s[0][row][x] + dp_s[1][row][x] + dp_s[2][row][x] + dp_s[3][row][x];
        dp_g[(size_t)(e0 + row) * 3 + x] = s;
    }
    __syncthreads();
    // q1 -> global (row layout, coalesced)
    for (int idx = tid; idx < 64 * 128; idx += 256) {
        int r = idx >> 7, cu = idx & 127;
        ((unsigned int*)&q1_g[(size_t)(e0 + r) * HD])[cu] = ((const unsigned int*)&X[r * 264])[cu];
    }
}

// ---------------- node kernel (R7-exact) ----------------
__global__ __launch_bounds__(256, 4) void node_kernel(
    const float* __restrict__ pos,
    const float* __restrict__ nb1, const float* __restrict__ nb2,
    const bf16x8* __restrict__ nw2p,
    const bf16* __restrict__ q1_g, const uint2* __restrict__ p1_g,
    const float* __restrict__ dp_g,
    float* __restrict__ h_out, float* __restrict__ pos_out) {
    __shared__ bf16 X[65 * 264];   // q1 halo (slot t = q1[n0-1+t]) -> t4 rows 0..63

    const int tid = threadIdx.x;
    const int lane = tid & 63, wave = tid >> 6;
    const int lrow = lane & 15, lkhi = lane >> 4;
    const int n0 = blockIdx.x * 64;

    // pos head
    if (tid < 192) {
        int row = tid & 63, col = tid >> 6;
        int i = n0 + row;
        float dpi = (i < NN - 1) ? dp_g[(size_t)i * 3 + col] : 0.f;
        float dpm = (i > 0) ? dp_g[(size_t)(i - 1) * 3 + col] : 0.f;
        pos_out[(size_t)i * 3 + col] = pos[(size_t)i * 3 + col] + 0.1f * (dpi - dpm);
    }

    // stage q1 halo, uint4-vectorized
    for (int idx = tid; idx < 65 * 32; idx += 256) {
        int t = idx >> 5, cu = idx & 31;
        int er = n0 - 1 + t;
        uint4 v = make_uint4(0u, 0u, 0u, 0u);
        if (er >= 0 && er <= NN - 2) v = ((const uint4*)&q1_g[(size_t)er * HD])[cu];
        ((uint4*)&X[t * 264])[cu] = v;
    }
    // early p1 fragment loads (coalesced uint2)
    uint2 p1r[16];
    {
        const uint2* p1p = p1_g + ((size_t)blockIdx.x * 4 + wave) * 1024;
        #pragma unroll
        for (int i = 0; i < 16; ++i) p1r[i] = p1p[i * 64 + lane];
    }
    float b1[4];
    #pragma unroll
    for (int c = 0; c < 4; ++c) b1[c] = nb1[(wave * 4 + c) * 16 + lrow];
    __syncthreads();

    // elementwise t4 = silu(p1 + q1[i] + q1[i-1] + b1), held in regs
    unsigned int t4p[32];
    #pragma unroll
    for (int r = 0; r < 4; ++r)
        #pragma unroll
        for (int c = 0; c < 4; ++c) {
            int i = r * 4 + c;
            int col = (wave * 4 + c) * 16 + lrow;
            #pragma unroll
            for (int qh = 0; qh < 2; ++qh) {
                unsigned int pk = qh == 0 ? p1r[i].x : p1r[i].y;
                unsigned int outp = 0;
                #pragma unroll
                for (int j = 0; j < 2; ++j) {
                    int q = 2 * qh + j;
                    int row = r * 16 + lkhi * 4 + q;
                    float p1v = bfu2f(j == 0 ? (pk & 0xffffu) : (pk >> 16));
                    float z = p1v + (float)X[(row + 1) * 264 + col] + (float)X[row * 264 + col] + b1[c];
                    unsigned short tb = f2bfu(silu_f(z));
                    outp |= (unsigned int)tb << (16 * j);
                }
                t4p[i * 2 + qh] = outp;
            }
        }
    __syncthreads();  // all q1 reads done
    // write t4 tile (rows 0..63)
    #pragma unroll
    for (int r = 0; r < 4; ++r)
        #pragma unroll
        for (int c = 0; c < 4; ++c) {
            int i = r * 4 + c;
            int col = (wave * 4 + c) * 16 + lrow;
            #pragma unroll
            for (int q = 0; q < 4; ++q) {
                int row = r * 16 + lkhi * 4 + q;
                unsigned int pk = t4p[i * 2 + (q >> 1)];
                unsigned short tb = (unsigned short)((q & 1) ? (pk >> 16) : (pk & 0xffffu));
                X[row * 264 + col] = __builtin_bit_cast(bf16, tb);
            }
        }
    __syncthreads();

    // P2: h_out = t4 @ nw2 + nb2
    f32x4 acc[4][4];
    #pragma unroll
    for (int r = 0; r < 4; ++r)
        #pragma unroll
        for (int c = 0; c < 4; ++c) acc[r][c] = (f32x4)0.f;
    mm_tileR<8, 4>(X, 0, nw2p, wave, lane, acc);
    float b2[4];
    #pragma unroll
    for (int c = 0; c < 4; ++c) b2[c] = nb2[(wave * 4 + c) * 16 + lrow];
    #pragma unroll
    for (int r = 0; r < 4; ++r)
        #pragma unroll
        for (int c = 0; c < 4; ++c)
            #pragma unroll
            for (int q = 0; q < 4; ++q) {
                int row = r * 16 + lkhi * 4 + q;
                int col = (wave * 4 + c) * 16 + lrow;
                h_out[(size_t)(n0 + row) * HD + col] = acc[r][c][q] + b2[c];
            }
}

// ---------------- launch ----------------
extern "C" void kernel_launch(void* const* d_in, const int* in_sizes, int n_in,
                              void* d_out, int out_size, void* d_ws, size_t ws_size,
                              hipStream_t stream) {
    const float* h   = (const float*)d_in[0];
    const float* pos = (const float*)d_in[1];
    const float* ew1 = (const float*)d_in[2];
    const float* eb1 = (const float*)d_in[3];
    const float* ew2 = (const float*)d_in[4];
    const float* eb2 = (const float*)d_in[5];
    const float* pw1 = (const float*)d_in[6];
    const float* pb1 = (const float*)d_in[7];
    const float* pw2 = (const float*)d_in[8];
    const float* nw1 = (const float*)d_in[9];
    const float* nb1 = (const float*)d_in[10];
    const float* nw2 = (const float*)d_in[11];
    const float* nb2 = (const float*)d_in[12];

    char* ws = (char*)d_ws;
    bf16*  q1   = (bf16*)ws;                      // 67108864 B
    float* dp   = (float*)(ws + 67108864);        // 1572864 B
    uint2* p1   = (uint2*)(ws + 68681728);        // 67108864 B
    char*  wsw = ws + 135790592;
    bf16*  ew1p = (bf16*)(wsw);                   // 262144 B
    bf16*  ew2p = (bf16*)(wsw + 262144);          // 131072 B
    bf16*  pw1p = (bf16*)(wsw + 393216);          // 131072 B
    bf16*  nw1p = (bf16*)(wsw + 524288);          // 262144 B
    bf16*  nw2p = (bf16*)(wsw + 786432);          // 131072 B

    float* out = (float*)d_out;
    float* h_out = out;
    float* pos_out = out + (size_t)NN * HD;

    pack_kernel<<<1792, 256, 0, stream>>>(ew1, ew2, pw1, nw1, nw2,
                                          ew1p, ew2p, pw1p, nw1p, nw2p);
    edge_kernel<<<2048, 256, 0, stream>>>(h, pos, ew1, eb1, eb2, pb1, pw2,
                                          (const bf16x8*)ew1p, (const bf16x8*)ew2p,
                                          (const bf16x8*)pw1p, (const bf16x8*)nw1p,
                                          q1, p1, dp);
    node_kernel<<<2048, 256, 0, stream>>>(pos, nb1, nb2,
                                          (const bf16x8*)nw2p,
                                          q1, (const uint2*)p1, dp, h_out, pos_out);
}

// Round 14
// 238.569 us; speedup vs baseline: 1.5548x; 1.0881x over previous
//
#include <hip/hip_runtime.h>
#include <hip/hip_bf16.h>
#include <math.h>

#define NN 131072
#define HD 256

typedef __bf16 bf16;
typedef __attribute__((ext_vector_type(8))) __bf16 bf16x8;
typedef __attribute__((ext_vector_type(4))) __bf16 bf16x4;
typedef __attribute__((ext_vector_type(4))) float f32x4;

__device__ __forceinline__ float silu_f(float x) { return x / (1.f + __expf(-x)); }

__device__ __forceinline__ float bfu2f(unsigned int lo16) {
    unsigned int u = lo16 << 16;
    return __builtin_bit_cast(float, u);
}
__device__ __forceinline__ unsigned short f2bfu(float f) {
    bf16 b = (bf16)f;
    return __builtin_bit_cast(unsigned short, b);
}
__device__ __forceinline__ uint2 pack4(float a, float b, float c, float d) {
    uint2 v;
    v.x = (unsigned int)f2bfu(a) | ((unsigned int)f2bfu(b) << 16);
    v.y = (unsigned int)f2bfu(c) | ((unsigned int)f2bfu(d) << 16);
    return v;
}

// A-tile (LDS bf16, stride 264) x packed-B (global bf16x8) -> acc[RN][4].
// 2-deep B prefetch: next ks-step's B fragments load while current MFMAs issue.
template<int KSTEPS, int RN>
__device__ __forceinline__ void mm_tileR(const bf16* Xl, int bk0, const bf16x8* __restrict__ Bp,
                                         int wave, int lane, f32x4 acc[RN][4]) {
    const int lrow = lane & 15, lkhi = lane >> 4;
    bf16x8 bcur[4], bnxt[4];
    #pragma unroll
    for (int c = 0; c < 4; ++c)
        bcur[c] = Bp[(bk0 * 16 + wave * 4 + c) * 64 + lane];
    #pragma unroll
    for (int ks = 0; ks < KSTEPS; ++ks) {
        if (ks + 1 < KSTEPS) {
            #pragma unroll
            for (int c = 0; c < 4; ++c)
                bnxt[c] = Bp[((bk0 + ks + 1) * 16 + wave * 4 + c) * 64 + lane];
        }
        bf16x8 a[RN];
        #pragma unroll
        for (int r = 0; r < RN; ++r)
            a[r] = *(const bf16x8*)&Xl[(r * 16 + lrow) * 264 + ks * 32 + lkhi * 8];
        #pragma unroll
        for (int c = 0; c < 4; ++c)
            #pragma unroll
            for (int r = 0; r < RN; ++r)
                acc[r][c] = __builtin_amdgcn_mfma_f32_16x16x32_bf16(a[r], bcur[c], acc[r][c], 0, 0, 0);
        #pragma unroll
        for (int c = 0; c < 4; ++c) bcur[c] = bnxt[c];
    }
}

// ---------------- weight packing ----------------
__device__ __forceinline__ void packW(const float* __restrict__ W, bf16* __restrict__ P, int idx) {
    int j  = idx & 7;
    int ln = (idx >> 3) & 63;
    int cb = (idx >> 9) & 15;
    int ks = idx >> 13;
    int k = ks * 32 + ((ln >> 4) << 3) + j;
    int n = (cb << 4) + (ln & 15);
    P[idx] = (bf16)W[k * HD + n];
}

__global__ void pack_kernel(const float* __restrict__ ew1, const float* __restrict__ ew2,
                            const float* __restrict__ pw1, const float* __restrict__ nw1,
                            const float* __restrict__ nw2,
                            bf16* __restrict__ ew1p, bf16* __restrict__ ew2p,
                            bf16* __restrict__ pw1p, bf16* __restrict__ nw1p,
                            bf16* __restrict__ nw2p) {
    int t = blockIdx.x * 256 + threadIdx.x;
    if (t < 131072) { packW(ew1, ew1p, t); return; }
    t -= 131072;
    if (t < 65536)  { packW(ew2, ew2p, t); return; }
    t -= 65536;
    if (t < 65536)  { packW(pw1, pw1p, t); return; }
    t -= 65536;
    if (t < 131072) { packW(nw1, nw1p, t); return; }
    t -= 131072;
    if (t < 65536)  { packW(nw2, nw2p, t); return; }
}

// ---------------- edge kernel ----------------
// 64 edges/block, single LDS buffer, (256,3): unified-reg headroom for B-prefetch.
__global__ __launch_bounds__(256, 3) void edge_kernel(
    const float* __restrict__ h, const float* __restrict__ pos,
    const float* __restrict__ ew1, const float* __restrict__ eb1,
    const float* __restrict__ eb2, const float* __restrict__ pb1,
    const float* __restrict__ pw2,
    const bf16x8* __restrict__ ew1p, const bf16x8* __restrict__ ew2p,
    const bf16x8* __restrict__ pw1p, const bf16x8* __restrict__ nw1p,
    bf16* __restrict__ q1_g, uint2* __restrict__ p1_g,
    float* __restrict__ dp_g) {
    __shared__ bf16 X[65 * 264];          // h rows -> t1 -> ea -> q1 (in place)
    __shared__ float dist_s[64];
    __shared__ float dp_s[4][64][3];

    const int tid = threadIdx.x;
    const int lane = tid & 63, wave = tid >> 6;
    const int lrow = lane & 15, lkhi = lane >> 4;
    const int e0 = blockIdx.x * 64;

    // stage h rows e0..e0+64 (bf16)
    for (int idx = tid; idx < 65 * 64; idx += 256) {
        int r = idx >> 6, c4 = (idx & 63) << 2;
        int gr = e0 + r;
        float4 v = make_float4(0.f, 0.f, 0.f, 0.f);
        if (gr < NN) v = *(const float4*)&h[(size_t)gr * HD + c4];
        bf16x4 b;
        b[0] = (bf16)v.x; b[1] = (bf16)v.y; b[2] = (bf16)v.z; b[3] = (bf16)v.w;
        *(bf16x4*)&X[r * 264 + c4] = b;
    }
    if (tid < 64) {
        int e = e0 + tid;
        float d = 0.f;
        if (e < NN - 1) {
            float dx = pos[3 * e + 3] - pos[3 * e];
            float dy = pos[3 * e + 4] - pos[3 * e + 1];
            float dz = pos[3 * e + 5] - pos[3 * e + 2];
            d = sqrtf(dx * dx + dy * dy + dz * dz);
        }
        dist_s[tid] = d;
    }
    // per-lane uniform params
    float bias1[4], bias2[4], bias3[4], wlast[4], w2l[4][3];
    #pragma unroll
    for (int c = 0; c < 4; ++c) {
        int col = (wave * 4 + c) * 16 + lrow;
        bias1[c] = eb1[col];
        bias2[c] = eb2[col];
        bias3[c] = pb1[col];
        wlast[c] = ew1[512 * HD + col];
        #pragma unroll
        for (int x = 0; x < 3; ++x) w2l[c][x] = pw2[col * 3 + x];
    }
    __syncthreads();

    f32x4 acc[4][4];

    // phase 0: p1 = h_tile @ nw1[0:256] -> p1_g (uint2 fragment layout)
    #pragma unroll
    for (int r = 0; r < 4; ++r)
        #pragma unroll
        for (int c = 0; c < 4; ++c) acc[r][c] = (f32x4)0.f;
    mm_tileR<8, 4>(X, 0, nw1p, wave, lane, acc);
    {
        uint2* p1w = p1_g + ((size_t)blockIdx.x * 4 + wave) * 1024;
        #pragma unroll
        for (int r = 0; r < 4; ++r)
            #pragma unroll
            for (int c = 0; c < 4; ++c) {
                uint2 v;
                v.x = (unsigned int)f2bfu(acc[r][c][0]) | ((unsigned int)f2bfu(acc[r][c][1]) << 16);
                v.y = (unsigned int)f2bfu(acc[r][c][2]) | ((unsigned int)f2bfu(acc[r][c][3]) << 16);
                p1w[(r * 4 + c) * 64 + lane] = v;
            }
    }

    // phase 1: t1 = silu(edge_feat @ ew1 + eb1); K=512 via row shift rb; 2-deep B prefetch
    #pragma unroll
    for (int r = 0; r < 4; ++r)
        #pragma unroll
        for (int c = 0; c < 4; ++c) acc[r][c] = (f32x4)0.f;
    {
        bf16x8 bcur[4], bnxt[4];
        #pragma unroll
        for (int c = 0; c < 4; ++c)
            bcur[c] = ew1p[(wave * 4 + c) * 64 + lane];
        #pragma unroll
        for (int ks = 0; ks < 16; ++ks) {
            if (ks < 15) {
                #pragma unroll
                for (int c = 0; c < 4; ++c)
                    bnxt[c] = ew1p[((ks + 1) * 16 + wave * 4 + c) * 64 + lane];
            }
            const int rb = (ks >= 8) ? 1 : 0;
            const int kk = ks * 32 + lkhi * 8 - rb * 256;
            bf16x8 a[4];
            #pragma unroll
            for (int r = 0; r < 4; ++r)
                a[r] = *(const bf16x8*)&X[(r * 16 + lrow + rb) * 264 + kk];
            #pragma unroll
            for (int c = 0; c < 4; ++c)
                #pragma unroll
                for (int r = 0; r < 4; ++r)
                    acc[r][c] = __builtin_amdgcn_mfma_f32_16x16x32_bf16(a[r], bcur[c], acc[r][c], 0, 0, 0);
            #pragma unroll
            for (int c = 0; c < 4; ++c) bcur[c] = bnxt[c];
        }
    }
    __syncthreads();  // all phase-0/1 reads of X done
    #pragma unroll
    for (int r = 0; r < 4; ++r)
        #pragma unroll
        for (int c = 0; c < 4; ++c)
            #pragma unroll
            for (int q = 0; q < 4; ++q) {
                int row = r * 16 + lkhi * 4 + q;
                int col = (wave * 4 + c) * 16 + lrow;
                float v = acc[r][c][q] + dist_s[row] * wlast[c] + bias1[c];
                X[row * 264 + col] = (bf16)silu_f(v);  // t1 in place
            }
    __syncthreads();

    // phase 2: ea = t1 @ ew2 + eb2 (in place)
    #pragma unroll
    for (int r = 0; r < 4; ++r)
        #pragma unroll
        for (int c = 0; c < 4; ++c) acc[r][c] = (f32x4)0.f;
    mm_tileR<8, 4>(X, 0, ew2p, wave, lane, acc);
    __syncthreads();
    #pragma unroll
    for (int r = 0; r < 4; ++r)
        #pragma unroll
        for (int c = 0; c < 4; ++c)
            #pragma unroll
            for (int q = 0; q < 4; ++q) {
                int row = r * 16 + lkhi * 4 + q;
                int col = (wave * 4 + c) * 16 + lrow;
                X[row * 264 + col] = (bf16)(acc[r][c][q] + bias2[c]);  // ea in place
            }
    __syncthreads();

    // phase 3a: t3 = silu(ea @ pw1 + pb1) in regs; dp partials -> dp_s
    #pragma unroll
    for (int r = 0; r < 4; ++r)
        #pragma unroll
        for (int c = 0; c < 4; ++c) acc[r][c] = (f32x4)0.f;
    mm_tileR<8, 4>(X, 0, pw1p, wave, lane, acc);
    #pragma unroll
    for (int r = 0; r < 4; ++r) {
        float red[12];
        #pragma unroll
        for (int q = 0; q < 4; ++q) {
            float t3v[4];
            #pragma unroll
            for (int c = 0; c < 4; ++c) t3v[c] = silu_f(acc[r][c][q] + bias3[c]);
            #pragma unroll
            for (int x = 0; x < 3; ++x) {
                float s = 0.f;
                #pragma unroll
                for (int c = 0; c < 4; ++c) s += t3v[c] * w2l[c][x];
                red[q * 3 + x] = s;
            }
        }
        #pragma unroll
        for (int i = 0; i < 12; ++i) {
            float v = red[i];
            v += __shfl_xor(v, 1);
            v += __shfl_xor(v, 2);
            v += __shfl_xor(v, 4);
            v += __shfl_xor(v, 8);
            red[i] = v;
        }
        if (lrow == 0) {
            #pragma unroll
            for (int q = 0; q < 4; ++q)
                #pragma unroll
                for (int x = 0; x < 3; ++x)
                    dp_s[wave][r * 16 + lkhi * 4 + q][x] = red[q * 3 + x];
        }
    }

    // phase 3b: q1 = ea @ nw1[256:512] (same X state — no barrier needed)
    #pragma unroll
    for (int r = 0; r < 4; ++r)
        #pragma unroll
        for (int c = 0; c < 4; ++c) acc[r][c] = (f32x4)0.f;
    mm_tileR<8, 4>(X, 8, nw1p, wave, lane, acc);

    __syncthreads();  // all X reads done + dp_s visible
    // overlay X = q1
    #pragma unroll
    for (int r = 0; r < 4; ++r)
        #pragma unroll
        for (int c = 0; c < 4; ++c)
            #pragma unroll
            for (int q = 0; q < 4; ++q) {
                int row = r * 16 + lkhi * 4 + q;
                int col = (wave * 4 + c) * 16 + lrow;
                X[row * 264 + col] = (bf16)acc[r][c][q];
            }
    if (tid < 192) {
        int row = tid / 3, x = tid - row * 3;
        float s = dp_s[0][row][x] + dp_s[1][row][x] + dp_s[2][row][x] + dp_s[3][row][x];
        dp_g[(size_t)(e0 + row) * 3 + x] = s;
    }
    __syncthreads();
    // q1 -> global (row layout, coalesced)
    for (int idx = tid; idx < 64 * 128; idx += 256) {
        int r = idx >> 7, cu = idx & 127;
        ((unsigned int*)&q1_g[(size_t)(e0 + r) * HD])[cu] = ((const unsigned int*)&X[r * 264])[cu];
    }
}

// ---------------- node kernel ----------------
// t4 = silu(p1[i] + q1[i] + q1[i-1] + nb1); h_out = t4 @ nw2 + nb2.
__global__ __launch_bounds__(256, 4) void node_kernel(
    const float* __restrict__ pos,
    const float* __restrict__ nb1, const float* __restrict__ nb2,
    const bf16x8* __restrict__ nw2p,
    const bf16* __restrict__ q1_g, const uint2* __restrict__ p1_g,
    const float* __restrict__ dp_g,
    float* __restrict__ h_out, float* __restrict__ pos_out) {
    __shared__ bf16 X[65 * 264];   // q1 halo (slot t = q1[n0-1+t]) -> t4 rows 0..63

    const int tid = threadIdx.x;
    const int lane = tid & 63, wave = tid >> 6;
    const int lrow = lane & 15, lkhi = lane >> 4;
    const int n0 = blockIdx.x * 64;

    // pos head
    if (tid < 192) {
        int row = tid & 63, col = tid >> 6;
        int i = n0 + row;
        float dpi = (i < NN - 1) ? dp_g[(size_t)i * 3 + col] : 0.f;
        float dpm = (i > 0) ? dp_g[(size_t)(i - 1) * 3 + col] : 0.f;
        pos_out[(size_t)i * 3 + col] = pos[(size_t)i * 3 + col] + 0.1f * (dpi - dpm);
    }

    // stage q1 halo, uint4-vectorized
    for (int idx = tid; idx < 65 * 32; idx += 256) {
        int t = idx >> 5, cu = idx & 31;
        int er = n0 - 1 + t;
        uint4 v = make_uint4(0u, 0u, 0u, 0u);
        if (er >= 0 && er <= NN - 2) v = ((const uint4*)&q1_g[(size_t)er * HD])[cu];
        ((uint4*)&X[t * 264])[cu] = v;
    }
    // early p1 fragment loads (coalesced uint2)
    uint2 p1r[16];
    {
        const uint2* p1p = p1_g + ((size_t)blockIdx.x * 4 + wave) * 1024;
        #pragma unroll
        for (int i = 0; i < 16; ++i) p1r[i] = p1p[i * 64 + lane];
    }
    float b1[4];
    #pragma unroll
    for (int c = 0; c < 4; ++c) b1[c] = nb1[(wave * 4 + c) * 16 + lrow];
    __syncthreads();

    // elementwise t4 = silu(p1 + q1[i] + q1[i-1] + b1), held in regs
    unsigned int t4p[32];
    #pragma unroll
    for (int r = 0; r < 4; ++r)
        #pragma unroll
        for (int c = 0; c < 4; ++c) {
            int i = r * 4 + c;
            int col = (wave * 4 + c) * 16 + lrow;
            #pragma unroll
            for (int qh = 0; qh < 2; ++qh) {
                unsigned int pk = qh == 0 ? p1r[i].x : p1r[i].y;
                unsigned int outp = 0;
                #pragma unroll
                for (int j = 0; j < 2; ++j) {
                    int q = 2 * qh + j;
                    int row = r * 16 + lkhi * 4 + q;
                    float p1v = bfu2f(j == 0 ? (pk & 0xffffu) : (pk >> 16));
                    float z = p1v + (float)X[(row + 1) * 264 + col] + (float)X[row * 264 + col] + b1[c];
                    unsigned short tb = f2bfu(silu_f(z));
                    outp |= (unsigned int)tb << (16 * j);
                }
                t4p[i * 2 + qh] = outp;
            }
        }
    __syncthreads();  // all q1 reads done
    // write t4 tile (rows 0..63)
    #pragma unroll
    for (int r = 0; r < 4; ++r)
        #pragma unroll
        for (int c = 0; c < 4; ++c) {
            int i = r * 4 + c;
            int col = (wave * 4 + c) * 16 + lrow;
            #pragma unroll
            for (int q = 0; q < 4; ++q) {
                int row = r * 16 + lkhi * 4 + q;
                unsigned int pk = t4p[i * 2 + (q >> 1)];
                unsigned short tb = (unsigned short)((q & 1) ? (pk >> 16) : (pk & 0xffffu));
                X[row * 264 + col] = __builtin_bit_cast(bf16, tb);
            }
        }
    __syncthreads();

    // P2: h_out = t4 @ nw2 + nb2
    f32x4 acc[4][4];
    #pragma unroll
    for (int r = 0; r < 4; ++r)
        #pragma unroll
        for (int c = 0; c < 4; ++c) acc[r][c] = (f32x4)0.f;
    mm_tileR<8, 4>(X, 0, nw2p, wave, lane, acc);
    float b2[4];
    #pragma unroll
    for (int c = 0; c < 4; ++c) b2[c] = nb2[(wave * 4 + c) * 16 + lrow];
    #pragma unroll
    for (int r = 0; r < 4; ++r)
        #pragma unroll
        for (int c = 0; c < 4; ++c)
            #pragma unroll
            for (int q = 0; q < 4; ++q) {
                int row = r * 16 + lkhi * 4 + q;
                int col = (wave * 4 + c) * 16 + lrow;
                h_out[(size_t)(n0 + row) * HD + col] = acc[r][c][q] + b2[c];
            }
}

// ---------------- launch ----------------
extern "C" void kernel_launch(void* const* d_in, const int* in_sizes, int n_in,
                              void* d_out, int out_size, void* d_ws, size_t ws_size,
                              hipStream_t stream) {
    const float* h   = (const float*)d_in[0];
    const float* pos = (const float*)d_in[1];
    const float* ew1 = (const float*)d_in[2];
    const float* eb1 = (const float*)d_in[3];
    const float* ew2 = (const float*)d_in[4];
    const float* eb2 = (const float*)d_in[5];
    const float* pw1 = (const float*)d_in[6];
    const float* pb1 = (const float*)d_in[7];
    const float* pw2 = (const float*)d_in[8];
    const float* nw1 = (const float*)d_in[9];
    const float* nb1 = (const float*)d_in[10];
    const float* nw2 = (const float*)d_in[11];
    const float* nb2 = (const float*)d_in[12];

    char* ws = (char*)d_ws;
    bf16*  q1   = (bf16*)ws;                      // 67108864 B
    float* dp   = (float*)(ws + 67108864);        // 1572864 B
    uint2* p1   = (uint2*)(ws + 68681728);        // 67108864 B
    char*  wsw = ws + 135790592;
    bf16*  ew1p = (bf16*)(wsw);                   // 262144 B
    bf16*  ew2p = (bf16*)(wsw + 262144);          // 131072 B
    bf16*  pw1p = (bf16*)(wsw + 393216);          // 131072 B
    bf16*  nw1p = (bf16*)(wsw + 524288);          // 262144 B
    bf16*  nw2p = (bf16*)(wsw + 786432);          // 131072 B

    float* out = (float*)d_out;
    float* h_out = out;
    float* pos_out = out + (size_t)NN * HD;

    pack_kernel<<<1792, 256, 0, stream>>>(ew1, ew2, pw1, nw1, nw2,
                                          ew1p, ew2p, pw1p, nw1p, nw2p);
    edge_kernel<<<2048, 256, 0, stream>>>(h, pos, ew1, eb1, eb2, pb1, pw2,
                                          (const bf16x8*)ew1p, (const bf16x8*)ew2p,
                                          (const bf16x8*)pw1p, (const bf16x8*)nw1p,
                                          q1, p1, dp);
    node_kernel<<<2048, 256, 0, stream>>>(pos, nb1, nb2,
                                          (const bf16x8*)nw2p,
                                          q1, (const uint2*)p1, dp, h_out, pos_out);
}